// Round 4
// baseline (152.922 us; speedup 1.0000x reference)
//
#include <hip/hip_runtime.h>
#include <math.h>

#define T_STEPS 64
#define BATCH   256
#define NX      512
#define NH      512

typedef short bf16x8 __attribute__((ext_vector_type(8)));
typedef float f32x4  __attribute__((ext_vector_type(4)));

// f32 -> bf16 round-to-nearest-even (bit trick, no NaN inputs here)
__device__ __forceinline__ unsigned short f2bf(float f) {
    union { float f; unsigned u; } v; v.f = f;
    unsigned r = v.u + 0x7fffu + ((v.u >> 16) & 1u);
    return (unsigned short)(r >> 16);
}

// ---------------------------------------------------------------------------
// Kernel 1: P[r][h] = b1[h] + sum_k X[r][k] * W1[h][k]   (bf16 MFMA, f32 acc)
//   (unchanged from round 3 — verified correct)
// ---------------------------------------------------------------------------
__global__ __launch_bounds__(256, 2) void gemm_bf16_kernel(
    const float* __restrict__ X,    // [16384][512]
    const float* __restrict__ W1,   // [512][512]
    const float* __restrict__ b1,   // [512]
    float* __restrict__ P)          // [16384][512]
{
    __shared__ unsigned short lds[16384];   // 32 KB: A = [0,8192), B = [8192,16384)

    const int tid  = threadIdx.x;
    const int lane = tid & 63;
    const int wave = tid >> 6;
    const int wm   = wave >> 1;
    const int wn   = wave & 1;
    const int rbase = blockIdx.x * 128;
    const int nbase = blockIdx.y * 128;

    f32x4 acc[4][4] = {};

    for (int kb = 0; kb < 512; kb += 64) {
#pragma unroll
        for (int i = 0; i < 8; ++i) {
            int g   = tid + (i & 3) * 256;
            int ks  = g >> 9;
            int ms  = (g >> 6) & 7;
            int l   = g & 63;
            int row = ms * 16 + (l & 15);
            int kof = kb + ks * 32 + (l >> 4) * 8;
            const float* src = (i < 4) ? &X[(size_t)(rbase + row) * 512 + kof]
                                       : &W1[(size_t)(nbase + row) * 512 + kof];
            float4 v0 = *(const float4*)src;
            float4 v1 = *(const float4*)(src + 4);
            unsigned p0 = (unsigned)f2bf(v0.x) | ((unsigned)f2bf(v0.y) << 16);
            unsigned p1 = (unsigned)f2bf(v0.z) | ((unsigned)f2bf(v0.w) << 16);
            unsigned p2 = (unsigned)f2bf(v1.x) | ((unsigned)f2bf(v1.y) << 16);
            unsigned p3 = (unsigned)f2bf(v1.z) | ((unsigned)f2bf(v1.w) << 16);
            int4 pk = make_int4((int)p0, (int)p1, (int)p2, (int)p3);
            *(int4*)&lds[((i < 4) ? 0 : 8192) + g * 8] = pk;
        }
        __syncthreads();

#pragma unroll
        for (int ks = 0; ks < 2; ++ks) {
            bf16x8 afr[4], bfr[4];
#pragma unroll
            for (int mf = 0; mf < 4; ++mf)
                afr[mf] = *(const bf16x8*)&lds[((ks * 8 + wm * 4 + mf) * 64 + lane) * 8];
#pragma unroll
            for (int nf = 0; nf < 4; ++nf)
                bfr[nf] = *(const bf16x8*)&lds[8192 + ((ks * 8 + wn * 4 + nf) * 64 + lane) * 8];
#pragma unroll
            for (int mf = 0; mf < 4; ++mf)
#pragma unroll
                for (int nf = 0; nf < 4; ++nf)
                    acc[mf][nf] = __builtin_amdgcn_mfma_f32_16x16x32_bf16(
                        afr[mf], bfr[nf], acc[mf][nf], 0, 0, 0);
        }
        __syncthreads();
    }

    float bc[4];
#pragma unroll
    for (int nf = 0; nf < 4; ++nf)
        bc[nf] = b1[nbase + wn * 64 + nf * 16 + (lane & 15)];
#pragma unroll
    for (int mf = 0; mf < 4; ++mf) {
#pragma unroll
        for (int nf = 0; nf < 4; ++nf) {
#pragma unroll
            for (int r = 0; r < 4; ++r) {
                int m = rbase + wm * 64 + mf * 16 + ((lane >> 4) << 2) + r;
                int n = nbase + wn * 64 + nf * 16 + (lane & 15);
                P[(size_t)m * 512 + n] = acc[mf][nf][r] + bc[nf];
            }
        }
    }
}

// ---------------------------------------------------------------------------
// Kernel 2: per-batch Gram (unchanged from round 3 — verified correct)
// ---------------------------------------------------------------------------
__global__ __launch_bounds__(256) void gram_kernel(
    const float* __restrict__ X,    // [T][B][NX]
    float* __restrict__ Gt)         // [B][64][64]
{
    const int b   = blockIdx.x;
    const int tid = threadIdx.x;
    __shared__ float Xs[64][516];

    for (int idx = tid; idx < 64 * 128; idx += 256) {
        int t  = idx >> 7;
        int c4 = (idx & 127) << 2;
        *(float4*)&Xs[t][c4] = *(const float4*)&X[((size_t)t * BATCH + b) * NX + c4];
    }
    __syncthreads();

    const int a  = tid >> 4;
    const int bb = tid & 15;

    float acc[4][4] = {};
#pragma unroll 2
    for (int k = 0; k < 512; k += 4) {
        float4 sv[4], tv[4];
#pragma unroll
        for (int i = 0; i < 4; ++i) sv[i] = *(const float4*)&Xs[a * 4 + i][k];
#pragma unroll
        for (int j = 0; j < 4; ++j) tv[j] = *(const float4*)&Xs[bb + 16 * j][k];
#pragma unroll
        for (int i = 0; i < 4; ++i)
#pragma unroll
            for (int j = 0; j < 4; ++j)
                acc[i][j] += sv[i].x * tv[j].x + sv[i].y * tv[j].y
                           + sv[i].z * tv[j].z + sv[i].w * tv[j].w;
    }
#pragma unroll
    for (int j = 0; j < 4; ++j)
#pragma unroll
        for (int i = 0; i < 4; ++i)
            Gt[((size_t)b * 64 + (bb + 16 * j)) * 64 + (a * 4 + i)] = acc[i][j];
}

// ---------------------------------------------------------------------------
// Kernel 3: scan — REWRITTEN.
//   One block per batch, 512 threads = one per hidden unit.
//   * Rolled t-loop (small, I-cache-resident body).
//   * History in LDS Hs[64][512]: column h is written and read ONLY by
//     thread h (stride-1 across lanes -> conflict-free, race-free).
//   * coeff[s] = eta * lam^{t-1-s} * G[t][s] double-buffered by step parity,
//     written ONE STEP AHEAD by threads h<64 from a G row prefetched TWO
//     steps ahead. lam powers via per-thread running pw (no table).
//   * P[t+1] prefetched one step ahead.
//   * Zero-initialized coeff/Hs let the 4-wide history loop read past t
//     without tail code (extra terms are 0*0).
//   * ONE __syncthreads per step (orders coeff & red only).
//   * a2 finish: 8 wave partials -> 4 uniform ds_read_b128 + adds
//     (deterministic, no atomics).
// ---------------------------------------------------------------------------
__global__ __launch_bounds__(512, 1) void scan_kernel(
    const float* __restrict__ P,    // [T][B][NH]  (== outH, aliased; same-thread
    const float* __restrict__ Gt,   //  read-before-write per address)
    const float* __restrict__ w2,   // [NH][2]
    const float* __restrict__ b2,   // [2]
    const float* __restrict__ w21,  // [NH][2]
    const float* __restrict__ lamp,
    const float* __restrict__ etap,
    float* __restrict__ outH,       // [T][B][NH]
    float* __restrict__ outY)       // [T][B][2]
{
    const int b = blockIdx.x;
    const int h = threadIdx.x;

    __shared__ float Hs[64][512];   // 128 KB history; col h private to thread h
    __shared__ float coeff[2][64];
    __shared__ float red[2][16];

    // ---- zero-init LDS (Hs rows via float4; 8 threads per row)
    {
        int r = h & 63, c = (h >> 6) * 64;
        float4 z = make_float4(0.f, 0.f, 0.f, 0.f);
#pragma unroll
        for (int j = 0; j < 16; ++j)
            *(float4*)&Hs[r][c + j * 4] = z;
        if (h < 128) coeff[h >> 6][h & 63] = 0.f;
        if (h < 32)  ((float*)red)[h] = 0.f;
    }

    const float eta = etap[0];
    const float lam = fminf(lamp[0], 1.0f);
    const float2 w21v = *(const float2*)&w21[2 * h];
    const float2 w2v  = *(const float2*)&w2[2 * h];
    const float b20 = b2[0], b21 = b2[1];
    const float* gb = Gt + (size_t)b * 4096;

    float pv = P[(size_t)b * NH + h];                  // P[0]
    float g_cur = (h < 64) ? gb[64 + h] : 0.f;         // G[1][h]
    float g_nxt = 0.f;
    float pv_next = 0.f;
    float pw = 1.0f;                                   // lam^(t-h) for coeff
    float a2x = 0.f, a2y = 0.f;

    __syncthreads();

#pragma unroll 1
    for (int t = 0; t < T_STEPS; ++t) {
        const int par = t & 1;

        // prefetches for future steps (issued early, consumed later)
        if (t < 63)
            pv_next = P[(size_t)(t + 1) * (BATCH * NH) + (size_t)b * NH + h];
        if (h < 64 && t < 62)
            g_nxt = gb[(t + 2) * 64 + h];

        // history term: sum_{s<t} coeff[s] * h_s[h]  (4-wide, zero-padded)
        float ac0 = 0.f, ac1 = 0.f, ac2 = 0.f, ac3 = 0.f;
        for (int s = 0; s < t; s += 4) {
            float4 cf = *(const float4*)&coeff[par][s];
            ac0 = fmaf(cf.x, Hs[s][h],     ac0);
            ac1 = fmaf(cf.y, Hs[s + 1][h], ac1);
            ac2 = fmaf(cf.z, Hs[s + 2][h], ac2);
            ac3 = fmaf(cf.w, Hs[s + 3][h], ac3);
        }

        float a1 = pv + w21v.x * a2x + w21v.y * a2y + ((ac0 + ac1) + (ac2 + ac3));
        float hv = 1.0f / (1.0f + __expf(-a1));

        Hs[t][h] = hv;
        outH[(size_t)t * (BATCH * NH) + (size_t)b * NH + h] = hv;

        // wave-level reduce of (hv*w2) -> 8 partials
        float p0 = hv * w2v.x;
        float p1 = hv * w2v.y;
#pragma unroll
        for (int off = 32; off; off >>= 1) {
            p0 += __shfl_down(p0, off);
            p1 += __shfl_down(p1, off);
        }
        if ((h & 63) == 0) {
            red[par][(h >> 6) * 2]     = p0;
            red[par][(h >> 6) * 2 + 1] = p1;
        }

        // write next step's coeff (uses G row prefetched 2 steps ago)
        if (h <= t && h < 64 && t < 63) {
            coeff[par ^ 1][h] = eta * pw * g_cur;
            pw *= lam;
        }

        __syncthreads();

        // finish a2 for step t+1 (uniform LDS broadcasts, deterministic)
        float4 r0 = *(const float4*)&red[par][0];
        float4 r1 = *(const float4*)&red[par][4];
        float4 r2 = *(const float4*)&red[par][8];
        float4 r3 = *(const float4*)&red[par][12];
        float s0 = b20 + ((r0.x + r0.z) + (r1.x + r1.z)) + ((r2.x + r2.z) + (r3.x + r3.z));
        float s1 = b21 + ((r0.y + r0.w) + (r1.y + r1.w)) + ((r2.y + r2.w) + (r3.y + r3.w));
        if (h == 0) {
            outY[((size_t)t * BATCH + b) * 2 + 0] = 1.0f / (1.0f + __expf(-s0));
            outY[((size_t)t * BATCH + b) * 2 + 1] = 1.0f / (1.0f + __expf(-s1));
        }
        a2x = s0; a2y = s1;
        pv = pv_next;
        g_cur = g_nxt;
    }
}

// ---------------------------------------------------------------------------
extern "C" void kernel_launch(void* const* d_in, const int* in_sizes, int n_in,
                              void* d_out, int out_size, void* d_ws, size_t ws_size,
                              hipStream_t stream) {
    const float* x   = (const float*)d_in[0];
    const float* w1  = (const float*)d_in[1];
    const float* b1  = (const float*)d_in[2];
    const float* w2  = (const float*)d_in[3];
    const float* b2  = (const float*)d_in[4];
    const float* w21 = (const float*)d_in[5];
    const float* lam = (const float*)d_in[6];
    const float* eta = (const float*)d_in[7];

    float* outH = (float*)d_out;                       // [64*256*512], doubles as P
    float* outY = outH + (size_t)T_STEPS * BATCH * NH; // [64*256*2]
    float* Gt   = (float*)d_ws;                        // [256*64*64] = 4 MB

    gemm_bf16_kernel<<<dim3(128, 4), 256, 0, stream>>>(x, w1, b1, outH);
    gram_kernel<<<256, 256, 0, stream>>>(x, Gt);
    scan_kernel<<<256, 512, 0, stream>>>(outH, Gt, w2, b2, w21, lam, eta, outH, outY);
}